// Round 11
// baseline (409.073 us; speedup 1.0000x reference)
//
#include <hip/hip_runtime.h>

// Problem constants
#define B_   4
#define O_   1000
#define R_   20000
#define NF_  6
#define EDP_ 128   // ED=100 padded to 128
#define KS_  25    // k-split for aggregation
#define CHUNK_ 800 // R_/KS_
#define MPAD_ 1024 // M=1000 padded

// ws layout (in floats):
//   bmp : [10][80000][16]          = 12,800,000 floats (10 n-split slabs)
//   Et  : [4][128][20000] bf16     = 10,240,000 bf16 = 5,120,000 float slots
//   part: [25][4][1024][128] f32   = 13,107,200 floats
//   Wt  : ALIASES head of part region. Written by k_prep, read by k_mlp,
//         then overwritten by k_agg (stream-serial => safe).
// total = 31.0M floats = 124 MB
#define SLAB_    1280000   // 80000*16
#define NSLAB_   10
#define ET_OFF   12800000
#define PART_OFF 17920000
#define WT_USHORTS (4 * 2 * 25600)

typedef short bf16x8 __attribute__((ext_vector_type(8)));
typedef float f32x4  __attribute__((ext_vector_type(4)));
typedef unsigned short ushort4v __attribute__((ext_vector_type(4)));
typedef unsigned short ushort8v __attribute__((ext_vector_type(8)));

#define MFMA16 __builtin_amdgcn_mfma_f32_16x16x32_bf16

__device__ __forceinline__ unsigned short f2bf(float x) {
    union { float f; unsigned int u; } v; v.f = x;
    unsigned int r = (v.u + 0x7FFFu + ((v.u >> 16) & 1u)) >> 16;  // RNE
    return (unsigned short)r;
}

__device__ __forceinline__ float bf2f(unsigned short h) {
    union { unsigned int u; float f; } v; v.u = (unsigned int)h << 16;
    return v.f;
}

// ---------------- Kernel 0: weight prep (bf16 hi/lo transposed) -------------
__global__ __launch_bounds__(256) void k_prep(
    const float* __restrict__ rw1, const float* __restrict__ rb1,
    const float* __restrict__ rw2, const float* __restrict__ rb2,
    const float* __restrict__ rw3, const float* __restrict__ rb3,
    const float* __restrict__ rw4, const float* __restrict__ rb4,
    unsigned short* __restrict__ Wt, float* __restrict__ bfp)
{
    const int l = blockIdx.y;
    const float* Ws[4] = {rw1, rw2, rw3, rw4};
    const float* Bs[4] = {rb1, rb2, rb3, rb4};
    const int   Ksz[4] = {13, 150, 150, 150};
    const int   Nsz[4] = {150, 150, 150, 100};
    const float* w = Ws[l];
    const int K = Ksz[l], N = Nsz[l];

    int idx = blockIdx.x * 256 + threadIdx.x;   // 0..25599
    if (idx < 25600) {
        int n = idx / 160, k = idx % 160;
        float v = (k < K && n < N) ? w[k * N + n] : 0.f;
        unsigned short h = f2bf(v);
        unsigned short lo = f2bf(v - bf2f(h));
        Wt[(size_t)l * 51200 + idx]         = h;
        Wt[(size_t)l * 51200 + 25600 + idx] = lo;
    }
    if (blockIdx.x == 0 && threadIdx.x < 160)
        bfp[l * 160 + threadIdx.x] = (threadIdx.x < (unsigned)N) ? Bs[l][threadIdx.x] : 0.f;
}

// ---------------- Kernel 1: marshalling, de-paired S/RR phases --------------
// grid (20, 4, 10), 256 thr. IDENTICAL to the R10 kernel except the inner
// loop is split: phase 1 reads ONLY S (100 n's), phase 2 reads ONLY RR.
// Rationale: S and RR are 2MB-aligned equal-shape tensors, so same-offset
// paired loads always land on the SAME HBM channel; every prior marshal
// paired them back-to-back, halving effective channel coverage (the
// invariant ~1.9-2.0 TB/s wall across R0/R7/R8/R9/R10 regardless of
// granularity/occupancy/pipelining). k_agg (single-stream) gets ~2x more.
// Phase-split de-duplicates the in-flight channel set. Sum order within
// each stream is unchanged => bit-identical numerics vs R10.
__global__ __launch_bounds__(256) void k_marshal(
    const float* __restrict__ obj, const float* __restrict__ S,
    const float* __restrict__ RRm, const float* __restrict__ rinfo,
    float* __restrict__ bmp)
{
    __shared__ float sobj[100 * NF_];
    const int t = threadIdx.x;
    const int b = blockIdx.y, z = blockIdx.z;
    const int n0 = z * 100;

    for (int i = t; i < 100 * NF_; i += 256)
        sobj[i] = obj[(size_t)b * O_ * NF_ + (size_t)n0 * NF_ + i];
    __syncthreads();

    int r0 = blockIdx.x * 1024;
    if (r0 > R_ - 1024) r0 = R_ - 1024;   // block 19 overlaps 18: identical data
    const int rt = r0 + t * 4;

    const size_t base = (size_t)b * O_ * R_ + (size_t)n0 * R_ + rt;

    float ss[4][NF_] = {};
    float rs[4][NF_] = {};

    // ---- phase 1: S stream only
    {
        const float* Sp = S + base;
        #pragma unroll 4
        for (int n = 0; n < 100; ++n) {
            float4 sv = *(const float4*)(Sp + (size_t)n * R_);
            const float* o = &sobj[n * NF_];
            #pragma unroll
            for (int f = 0; f < NF_; ++f) {
                float ov = o[f];
                ss[0][f] = fmaf(sv.x, ov, ss[0][f]);
                ss[1][f] = fmaf(sv.y, ov, ss[1][f]);
                ss[2][f] = fmaf(sv.z, ov, ss[2][f]);
                ss[3][f] = fmaf(sv.w, ov, ss[3][f]);
            }
        }
    }
    // ---- phase 2: RR stream only
    {
        const float* Rp = RRm + base;
        #pragma unroll 4
        for (int n = 0; n < 100; ++n) {
            float4 rv = *(const float4*)(Rp + (size_t)n * R_);
            const float* o = &sobj[n * NF_];
            #pragma unroll
            for (int f = 0; f < NF_; ++f) {
                float ov = o[f];
                rs[0][f] = fmaf(rv.x, ov, rs[0][f]);
                rs[1][f] = fmaf(rv.y, ov, rs[1][f]);
                rs[2][f] = fmaf(rv.z, ov, rs[2][f]);
                rs[3][f] = fmaf(rv.w, ov, rs[3][f]);
            }
        }
    }

    float riv[4] = {0.f, 0.f, 0.f, 0.f};
    if (z == 0) {
        float4 ri = *(const float4*)(rinfo + (size_t)b * R_ + rt);
        riv[0] = ri.x; riv[1] = ri.y; riv[2] = ri.z; riv[3] = ri.w;
    }
    float* outp = bmp + (size_t)z * SLAB_ + ((size_t)b * R_ + rt) * 16;
    #pragma unroll
    for (int i = 0; i < 4; ++i) {
        float4 w0 = {ss[i][0], ss[i][1], ss[i][2], ss[i][3]};
        float4 w1 = {ss[i][4], ss[i][5], rs[i][0], rs[i][1]};
        float4 w2 = {rs[i][2], rs[i][3], rs[i][4], rs[i][5]};
        float4 w3 = {riv[i], 0.f, 0.f, 0.f};
        *(float4*)(outp + i * 16 + 0)  = w0;
        *(float4*)(outp + i * 16 + 4)  = w1;
        *(float4*)(outp + i * 16 + 8)  = w2;
        *(float4*)(outp + i * 16 + 12) = w3;
    }
}

// ---------------- Kernel 2: relational MLP via bf16 MFMA (64-row, proven) ---
template<int NT>
__device__ __forceinline__ void layer_mm(
    const unsigned short (*act)[168],
    const unsigned short* __restrict__ Wh, const unsigned short* __restrict__ Wl,
    int arow, int koff, int cl, f32x4* acc)
{
    #pragma unroll
    for (int n = 0; n < NT; ++n) acc[n] = (f32x4){0.f, 0.f, 0.f, 0.f};
    #pragma unroll
    for (int ks = 0; ks < 5; ++ks) {
        bf16x8 a = *(const bf16x8*)&act[arow][ks * 32 + koff];
        #pragma unroll
        for (int n = 0; n < NT; ++n) {
            bf16x8 wh = *(const bf16x8*)(Wh + (size_t)(n * 16 + cl) * 160 + ks * 32 + koff);
            bf16x8 wl = *(const bf16x8*)(Wl + (size_t)(n * 16 + cl) * 160 + ks * 32 + koff);
            acc[n] = MFMA16(a, wh, acc[n], 0, 0, 0);
            acc[n] = MFMA16(a, wl, acc[n], 0, 0, 0);
        }
    }
}

template<int NT>
__device__ __forceinline__ void epi(
    f32x4* acc, const float* __restrict__ bias,
    unsigned short (*out)[168], int m0, int cl, int rg0)
{
    __syncthreads();   // all waves done reading input acts
    #pragma unroll
    for (int n = 0; n < NT; ++n) {
        int col = n * 16 + cl;
        float bv = bias[col];
        #pragma unroll
        for (int rg = 0; rg < 4; ++rg) {
            float v = fmaxf(acc[n][rg] + bv, 0.f);
            out[m0 + rg0 + rg][col] = f2bf(v);
        }
    }
    __syncthreads();
}

__global__ __launch_bounds__(256) void k_mlp(
    const float* __restrict__ bmp, unsigned short* __restrict__ Et,
    const unsigned short* __restrict__ Wt, const float* __restrict__ bfp)
{
    __shared__ unsigned short act[64][168];   // single buffer, in-place layers
    __shared__ unsigned short alo[64][32];    // lo part of layer-1 input
    const int t = threadIdx.x;
    const size_t row0 = (size_t)blockIdx.x * 64;

    for (int idx = t; idx < 64 * 32; idx += 256) {
        int rr = idx >> 5, k = idx & 31;
        float v = 0.f;
        if (k < 13) {
            size_t e = (row0 + rr) * 16 + k;
            #pragma unroll
            for (int s = 0; s < NSLAB_; ++s)
                v += bmp[(size_t)s * SLAB_ + e];
        }
        unsigned short h = f2bf(v);
        act[rr][k] = h;
        alo[rr][k] = f2bf(v - bf2f(h));
    }
    __syncthreads();

    const int lane = t & 63, wave = t >> 6;
    const int m0   = wave * 16;
    const int arow = m0 + (lane & 15);
    const int koff = (lane >> 4) * 8;
    const int cl   = lane & 15;
    const int rg0  = (lane >> 4) * 4;

    f32x4 acc[10];

    // layer 1: K=32 (1 k-step), split A and split W (3 MFMA / tile)
    {
        const unsigned short* Wh = Wt;
        const unsigned short* Wl = Wt + 25600;
        bf16x8 ah = *(const bf16x8*)&act[arow][koff];
        bf16x8 al = *(const bf16x8*)&alo[arow][koff];
        #pragma unroll
        for (int n = 0; n < 10; ++n) {
            bf16x8 wh = *(const bf16x8*)(Wh + (size_t)(n * 16 + cl) * 160 + koff);
            bf16x8 wl = *(const bf16x8*)(Wl + (size_t)(n * 16 + cl) * 160 + koff);
            f32x4 a = (f32x4){0.f, 0.f, 0.f, 0.f};
            a = MFMA16(ah, wh, a, 0, 0, 0);
            a = MFMA16(ah, wl, a, 0, 0, 0);
            a = MFMA16(al, wh, a, 0, 0, 0);
            acc[n] = a;
        }
    }
    epi<10>(acc, bfp + 0 * 160, act, m0, cl, rg0);

    layer_mm<10>(act, Wt + 1 * 51200, Wt + 1 * 51200 + 25600, arow, koff, cl, acc);
    epi<10>(acc, bfp + 1 * 160, act, m0, cl, rg0);

    layer_mm<10>(act, Wt + 2 * 51200, Wt + 2 * 51200 + 25600, arow, koff, cl, acc);
    epi<10>(acc, bfp + 2 * 160, act, m0, cl, rg0);

    layer_mm<7>(act, Wt + 3 * 51200, Wt + 3 * 51200 + 25600, arow, koff, cl, acc);
    epi<7>(acc, bfp + 3 * 160, act, m0, cl, rg0);

    // write E transposed bf16: Et[b][j][r], rows j=100..127 zeroed
    for (int idx = t; idx < 64 * 128; idx += 256) {
        int rr = idx & 63, j = idx >> 6;
        size_t gr = row0 + rr;
        int b = (int)(gr / R_);
        int r = (int)(gr - (size_t)b * R_);
        Et[((size_t)(b * EDP_ + j)) * R_ + r] = (j < 100) ? act[rr][j] : (unsigned short)0;
    }
}

// ---------------- Kernel 3: aggregation, M=128 per block --------------------
// per (mt, b, kz): C[128x128] += RR[128 x 800] @ E[800 x 128]
// grid (8, 4, 25), 256 threads = 4 waves; wave w owns rows w*32..w*32+31
// (two 16-row m-groups), all 128 cols (8 n-tiles).
// A: direct per-lane global loads (+f2bf). B: double-buffered LDS
// [2][128][36] (18.4 KB), one barrier per k-step of 32, loads issued early.
__global__ __launch_bounds__(256) void k_agg(
    const float* __restrict__ RRm, const unsigned short* __restrict__ Et,
    float* __restrict__ part)
{
    __shared__ unsigned short sB[2][128][36];   // pad 36: 18-dword row stride
    const int t = threadIdx.x;
    const int mt = blockIdx.x, b = blockIdx.y, kz = blockIdx.z;
    const int lane = t & 63, wave = t >> 6;
    const int k0 = kz * CHUNK_;

    // B-stage: 128 rows x 32 bf16 per k-step = 512 x 16B chunks; 2 per thread
    const int br0 = t >> 2, bc0 = (t & 3) * 8;       // rows 0..63
    const int br1 = br0 + 64;                        // rows 64..127
    const unsigned short* EtB = Et + (size_t)b * EDP_ * R_;

    // A: two per-lane rows (m-groups), clamped (rows >=1000 dup 999; their
    // part rows are padding, never read by k_obj)
    const int cl = lane & 15, koff = (lane >> 4) * 8;
    int n0 = mt * 128 + wave * 32 + cl;
    int n1 = n0 + 16;
    if (n0 > 999) n0 = 999;
    if (n1 > 999) n1 = 999;
    const float* Ap0 = RRm + ((size_t)(b * O_) + n0) * R_ + k0 + koff;
    const float* Ap1 = RRm + ((size_t)(b * O_) + n1) * R_ + k0 + koff;

    f32x4 acc[2][8] = {};
    float4 a0c, a1c, a2c, a3c;
    float4 a0n = {0,0,0,0}, a1n = {0,0,0,0}, a2n = {0,0,0,0}, a3n = {0,0,0,0};

    // prologue: stage B + load A for iter 0
    {
        ushort8v v0 = *(const ushort8v*)(EtB + (size_t)br0 * R_ + k0 + bc0);
        ushort8v v1 = *(const ushort8v*)(EtB + (size_t)br1 * R_ + k0 + bc0);
        *(ushort8v*)&sB[0][br0][bc0] = v0;
        *(ushort8v*)&sB[0][br1][bc0] = v1;
        a0c = *(const float4*)(Ap0 + 0);
        a1c = *(const float4*)(Ap0 + 4);
        a2c = *(const float4*)(Ap1 + 0);
        a3c = *(const float4*)(Ap1 + 4);
    }
    __syncthreads();

    for (int it = 0; it < CHUNK_ / 32; ++it) {
        const int cur = it & 1, nxt = cur ^ 1;
        const bool more = (it + 1 < CHUNK_ / 32);
        ushort8v v0, v1;
        if (more) {
            // issue next-iter loads EARLY (hide HBM latency under MFMA phase)
            const int kb = k0 + (it + 1) * 32;
            v0 = *(const ushort8v*)(EtB + (size_t)br0 * R_ + kb + bc0);
            v1 = *(const ushort8v*)(EtB + (size_t)br1 * R_ + kb + bc0);
            a0n = *(const float4*)(Ap0 + (it + 1) * 32);
            a1n = *(const float4*)(Ap0 + (it + 1) * 32 + 4);
            a2n = *(const float4*)(Ap1 + (it + 1) * 32);
            a3n = *(const float4*)(Ap1 + (it + 1) * 32 + 4);
        }
        // convert A (cur) to bf16 fragments
        bf16x8 af0, af1;
        af0[0] = (short)f2bf(a0c.x); af0[1] = (short)f2bf(a0c.y);
        af0[2] = (short)f2bf(a0c.z); af0[3] = (short)f2bf(a0c.w);
        af0[4] = (short)f2bf(a1c.x); af0[5] = (short)f2bf(a1c.y);
        af0[6] = (short)f2bf(a1c.z); af0[7] = (short)f2bf(a1c.w);
        af1[0] = (short)f2bf(a2c.x); af1[1] = (short)f2bf(a2c.y);
        af1[2] = (short)f2bf(a2c.z); af1[3] = (short)f2bf(a2c.w);
        af1[4] = (short)f2bf(a3c.x); af1[5] = (short)f2bf(a3c.y);
        af1[6] = (short)f2bf(a3c.z); af1[7] = (short)f2bf(a3c.w);
        #pragma unroll
        for (int ni = 0; ni < 8; ++ni) {
            bf16x8 bf = *(const bf16x8*)&sB[cur][ni * 16 + cl][koff];
            acc[0][ni] = MFMA16(af0, bf, acc[0][ni], 0, 0, 0);
            acc[1][ni] = MFMA16(af1, bf, acc[1][ni], 0, 0, 0);
        }
        if (more) {
            *(ushort8v*)&sB[nxt][br0][bc0] = v0;
            *(ushort8v*)&sB[nxt][br1][bc0] = v1;
        }
        __syncthreads();
        a0c = a0n; a1c = a1n; a2c = a2n; a3c = a3n;
    }

    // store partials: C/D layout col=lane&15, row=(lane>>4)*4+rg
    float* pp = part + ((size_t)(kz * 4 + b) * MPAD_) * 128;
    #pragma unroll
    for (int mg = 0; mg < 2; ++mg) {
        const int rowb = mt * 128 + wave * 32 + mg * 16 + (lane >> 4) * 4;
        #pragma unroll
        for (int ni = 0; ni < 8; ++ni)
            #pragma unroll
            for (int rg = 0; rg < 4; ++rg)
                pp[(size_t)(rowb + rg) * 128 + ni * 16 + cl] = acc[mg][ni][rg];
    }
}

// ---------------- Kernel 4: object MLP (sums agg partials) ------------------
__global__ __launch_bounds__(256) void k_obj(
    const float* __restrict__ obj, const float* __restrict__ part,
    const float* __restrict__ ow1, const float* __restrict__ ob1,
    const float* __restrict__ ow2, const float* __restrict__ ob2,
    float* __restrict__ out)
{
    __shared__ float C[8][112];
    __shared__ float h[8][104];
    const int t = threadIdx.x;
    const int g0 = blockIdx.x * 8;

    for (int idx = t; idx < 8 * NF_; idx += 256) {
        int rr = idx / NF_, f = idx % NF_;
        C[rr][f] = obj[(size_t)(g0 + rr) * NF_ + f];
    }
    for (int idx = t; idx < 8 * 100; idx += 256) {
        int rr = idx / 100, f = idx % 100;
        int g = g0 + rr, b = g / 1000, n = g % 1000;
        float s = 0.f;
        for (int z = 0; z < KS_; ++z)
            s += part[((size_t)(z * 4 + b) * MPAD_ + n) * 128 + f];
        C[rr][6 + f] = s;
    }
    __syncthreads();

    for (int idx = t; idx < 8 * 100; idx += 256) {
        int rr = idx / 100, j = idx % 100;
        float acc = ob1[j];
        for (int k = 0; k < 106; ++k)
            acc = fmaf(C[rr][k], ow1[k * 100 + j], acc);
        h[rr][j] = fmaxf(acc, 0.f);
    }
    __syncthreads();

    if (t < 16) {
        int rr = t >> 1, j = t & 1;
        float acc = ob2[j];
        for (int k = 0; k < 100; ++k)
            acc = fmaf(h[rr][k], ow2[k * 2 + j], acc);
        out[(size_t)(g0 + rr) * 2 + j] = acc;
    }
}

// ---------------- launch ----------------------------------------------------
extern "C" void kernel_launch(void* const* d_in, const int* in_sizes, int n_in,
                              void* d_out, int out_size, void* d_ws, size_t ws_size,
                              hipStream_t stream)
{
    const float* obj   = (const float*)d_in[0];
    const float* S     = (const float*)d_in[1];
    const float* RRm   = (const float*)d_in[2];
    const float* rinfo = (const float*)d_in[3];
    const float* rw1   = (const float*)d_in[4];
    const float* rb1   = (const float*)d_in[5];
    const float* rw2   = (const float*)d_in[6];
    const float* rb2   = (const float*)d_in[7];
    const float* rw3   = (const float*)d_in[8];
    const float* rb3   = (const float*)d_in[9];
    const float* rw4   = (const float*)d_in[10];
    const float* rb4   = (const float*)d_in[11];
    const float* ow1   = (const float*)d_in[12];
    const float* ob1   = (const float*)d_in[13];
    const float* ow2   = (const float*)d_in[14];
    const float* ob2   = (const float*)d_in[15];

    float* ws            = (float*)d_ws;
    float* bmp           = ws;
    unsigned short* Et   = (unsigned short*)(ws + ET_OFF);
    float* part          = ws + PART_OFF;
    unsigned short* Wt   = (unsigned short*)(ws + PART_OFF);  // aliases part head
    float* bfp           = ws + PART_OFF + (WT_USHORTS / 2);
    float* out           = (float*)d_out;

    k_prep<<<dim3(100, 4), 256, 0, stream>>>(rw1, rb1, rw2, rb2, rw3, rb3, rw4, rb4,
                                             Wt, bfp);
    k_marshal<<<dim3(20, 4, 10), 256, 0, stream>>>(obj, S, RRm, rinfo, bmp);
    k_mlp<<<dim3(1250), 256, 0, stream>>>(bmp, Et, Wt, bfp);
    k_agg<<<dim3(8, 4, KS_), 256, 0, stream>>>(RRm, Et, part);
    k_obj<<<dim3(500), 256, 0, stream>>>(obj, part, ow1, ob1, ow2, ob2, out);
}

// Round 12
// 354.604 us; speedup vs baseline: 1.1536x; 1.1536x over previous
//
#include <hip/hip_runtime.h>

// Problem constants
#define B_   4
#define O_   1000
#define R_   20000
#define NF_  6
#define EDP_ 128   // ED=100 padded to 128
#define KS_  25    // k-split for aggregation
#define CHUNK_ 800 // R_/KS_
#define MPAD_ 1024 // M=1000 padded

// ws layout (in floats):
//   bmp : [2][80000][16]           = 2,560,000 floats
//   Et  : [4][128][20000] bf16     = 10,240,000 bf16 = 5,120,000 float slots
//   part: [25][4][1024][128] f32   = 13,107,200 floats
//   Wt  : ALIASES head of part region. Written by k_prep, read by k_mlp,
//         then overwritten by k_agg (stream-serial => safe).
#define ET_OFF   2560000
#define PART_OFF 7680000
#define WT_USHORTS (4 * 2 * 25600)

typedef short bf16x8 __attribute__((ext_vector_type(8)));
typedef float f32x4  __attribute__((ext_vector_type(4)));
typedef unsigned short ushort4v __attribute__((ext_vector_type(4)));
typedef unsigned short ushort8v __attribute__((ext_vector_type(8)));

#define MFMA16 __builtin_amdgcn_mfma_f32_16x16x32_bf16

__device__ __forceinline__ unsigned short f2bf(float x) {
    union { float f; unsigned int u; } v; v.f = x;
    unsigned int r = (v.u + 0x7FFFu + ((v.u >> 16) & 1u)) >> 16;  // RNE
    return (unsigned short)r;
}

__device__ __forceinline__ float bf2f(unsigned short h) {
    union { unsigned int u; float f; } v; v.u = (unsigned int)h << 16;
    return v.f;
}

// ---------------- Kernel 0: weight prep (bf16 hi/lo transposed) -------------
__global__ __launch_bounds__(256) void k_prep(
    const float* __restrict__ rw1, const float* __restrict__ rb1,
    const float* __restrict__ rw2, const float* __restrict__ rb2,
    const float* __restrict__ rw3, const float* __restrict__ rb3,
    const float* __restrict__ rw4, const float* __restrict__ rb4,
    unsigned short* __restrict__ Wt, float* __restrict__ bfp)
{
    const int l = blockIdx.y;
    const float* Ws[4] = {rw1, rw2, rw3, rw4};
    const float* Bs[4] = {rb1, rb2, rb3, rb4};
    const int   Ksz[4] = {13, 150, 150, 150};
    const int   Nsz[4] = {150, 150, 150, 100};
    const float* w = Ws[l];
    const int K = Ksz[l], N = Nsz[l];

    int idx = blockIdx.x * 256 + threadIdx.x;   // 0..25599
    if (idx < 25600) {
        int n = idx / 160, k = idx % 160;
        float v = (k < K && n < N) ? w[k * N + n] : 0.f;
        unsigned short h = f2bf(v);
        unsigned short lo = f2bf(v - bf2f(h));
        Wt[(size_t)l * 51200 + idx]         = h;
        Wt[(size_t)l * 51200 + 25600 + idx] = lo;
    }
    if (blockIdx.x == 0 && threadIdx.x < 160)
        bfp[l * 160 + threadIdx.x] = (threadIdx.x < (unsigned)N) ? Bs[l][threadIdx.x] : 0.f;
}

// ---------------- Kernel 1: marshalling (round-0 proven version, ~150us) ----
// Six restructurings (R7-R11) all failed to beat this: the n-row-walking
// pattern is ~2 TB/s on this part regardless of granularity/occupancy/
// pipelining/de-pairing. This variant is the measured-best at that floor.
__global__ __launch_bounds__(256) void k_marshal(
    const float* __restrict__ obj, const float* __restrict__ S,
    const float* __restrict__ RRm, const float* __restrict__ rinfo,
    float* __restrict__ bmp)
{
    __shared__ float sobj[500 * NF_];
    const int b = blockIdx.y, z = blockIdx.z;
    const int n0 = z * 500;
    for (int i = threadIdx.x; i < 500 * NF_; i += 256)
        sobj[i] = obj[(size_t)b * O_ * NF_ + (size_t)n0 * NF_ + i];
    __syncthreads();

    const int r = blockIdx.x * 256 + threadIdx.x;
    if (r >= R_) return;

    const size_t base = (size_t)b * O_ * R_ + (size_t)n0 * R_ + r;
    const float* Sp = S + base;
    const float* Rp = RRm + base;

    float ss[NF_] = {0.f, 0.f, 0.f, 0.f, 0.f, 0.f};
    float rs[NF_] = {0.f, 0.f, 0.f, 0.f, 0.f, 0.f};

    #pragma unroll 4
    for (int n = 0; n < 500; ++n) {
        float sv = Sp[(size_t)n * R_];
        float rv = Rp[(size_t)n * R_];
        #pragma unroll
        for (int f = 0; f < NF_; ++f) {
            float o = sobj[n * NF_ + f];
            ss[f] = fmaf(sv, o, ss[f]);
            rs[f] = fmaf(rv, o, rs[f]);
        }
    }

    float* outp = bmp + ((size_t)z * 80000 + (size_t)b * R_ + r) * 16;
    #pragma unroll
    for (int f = 0; f < NF_; ++f) {
        outp[f]     = ss[f];
        outp[6 + f] = rs[f];
    }
    outp[12] = (z == 0) ? rinfo[(size_t)b * R_ + r] : 0.f;
}

// ---------------- Kernel 2: relational MLP, 2M x 2N wave split --------------
// 64-row block, 4 waves = 2M x 2N. Wave owns 32 rows (2 m-frags) x 5 n-tiles.
// Per k-step: 10 weight loads feed 20 MFMAs (2:1, was 1:1), and block-level
// weight redundancy drops 4x -> 2x. Same LDS (25.6 KB, 6 blocks/CU), acc
// shrinks 40->40... acc[2][5] = 40 VGPR (R5's acc[2][10]=80 spilled).
// Numerics identical to the proven 64-row kernel (same fragments, same
// accumulation order per output element).
template<int NT>
__device__ __forceinline__ void layer_mmW(
    const unsigned short (*act)[168],
    const unsigned short* __restrict__ Wh, const unsigned short* __restrict__ Wl,
    int arow0, int koff, int cl, int nb, f32x4 (*acc)[5])
{
    #pragma unroll
    for (int m = 0; m < 2; ++m)
        #pragma unroll
        for (int j = 0; j < NT; ++j) acc[m][j] = (f32x4){0.f, 0.f, 0.f, 0.f};
    #pragma unroll
    for (int ks = 0; ks < 5; ++ks) {
        bf16x8 a0 = *(const bf16x8*)&act[arow0][ks * 32 + koff];
        bf16x8 a1 = *(const bf16x8*)&act[arow0 + 16][ks * 32 + koff];
        #pragma unroll
        for (int j = 0; j < NT; ++j) {
            const size_t wo = (size_t)((nb + j) * 16 + cl) * 160 + ks * 32 + koff;
            bf16x8 wh = *(const bf16x8*)(Wh + wo);
            bf16x8 wl = *(const bf16x8*)(Wl + wo);
            acc[0][j] = MFMA16(a0, wh, acc[0][j], 0, 0, 0);
            acc[0][j] = MFMA16(a0, wl, acc[0][j], 0, 0, 0);
            acc[1][j] = MFMA16(a1, wh, acc[1][j], 0, 0, 0);
            acc[1][j] = MFMA16(a1, wl, acc[1][j], 0, 0, 0);
        }
    }
}

template<int NT>
__device__ __forceinline__ void epiW(
    f32x4 (*acc)[5], const float* __restrict__ bias,
    unsigned short (*out)[168], int m0, int cl, int rg0, int nb)
{
    #pragma unroll
    for (int m = 0; m < 2; ++m) {
        #pragma unroll
        for (int j = 0; j < NT; ++j) {
            int col = (nb + j) * 16 + cl;
            float bv = bias[col];
            #pragma unroll
            for (int rg = 0; rg < 4; ++rg) {
                float v = fmaxf(acc[m][j][rg] + bv, 0.f);
                out[m0 + m * 16 + rg0 + rg][col] = f2bf(v);
            }
        }
    }
}

__global__ __launch_bounds__(256) void k_mlp(
    const float* __restrict__ bmp, unsigned short* __restrict__ Et,
    const unsigned short* __restrict__ Wt, const float* __restrict__ bfp)
{
    __shared__ unsigned short act[64][168];   // single buffer, in-place layers
    __shared__ unsigned short alo[64][32];    // lo part of layer-1 input
    const int t = threadIdx.x;
    const size_t row0 = (size_t)blockIdx.x * 64;

    for (int idx = t; idx < 64 * 32; idx += 256) {
        int rr = idx >> 5, k = idx & 31;
        float v = 0.f;
        if (k < 13)
            v = bmp[(row0 + rr) * 16 + k]
              + bmp[(size_t)80000 * 16 + (row0 + rr) * 16 + k];
        unsigned short h = f2bf(v);
        act[rr][k] = h;
        alo[rr][k] = f2bf(v - bf2f(h));
    }
    __syncthreads();

    const int lane = t & 63, wave = t >> 6;
    const int wm = wave >> 1, wn = wave & 1;
    const int m0    = wm * 32;
    const int arow0 = m0 + (lane & 15);
    const int koff  = (lane >> 4) * 8;
    const int cl    = lane & 15;
    const int rg0   = (lane >> 4) * 4;

    f32x4 acc[2][5];

    // ---- layer 1: K=32, split A and split W (3 MFMA per (m, n-tile))
    {
        const unsigned short* Wh = Wt;
        const unsigned short* Wl = Wt + 25600;
        bf16x8 ah0 = *(const bf16x8*)&act[arow0][koff];
        bf16x8 al0 = *(const bf16x8*)&alo[arow0][koff];
        bf16x8 ah1 = *(const bf16x8*)&act[arow0 + 16][koff];
        bf16x8 al1 = *(const bf16x8*)&alo[arow0 + 16][koff];
        #pragma unroll
        for (int j = 0; j < 5; ++j) {
            const size_t wo = (size_t)((wn * 5 + j) * 16 + cl) * 160 + koff;
            bf16x8 wh = *(const bf16x8*)(Wh + wo);
            bf16x8 wl = *(const bf16x8*)(Wl + wo);
            f32x4 a = (f32x4){0.f, 0.f, 0.f, 0.f};
            a = MFMA16(ah0, wh, a, 0, 0, 0);
            a = MFMA16(ah0, wl, a, 0, 0, 0);
            a = MFMA16(al0, wh, a, 0, 0, 0);
            acc[0][j] = a;
            f32x4 c = (f32x4){0.f, 0.f, 0.f, 0.f};
            c = MFMA16(ah1, wh, c, 0, 0, 0);
            c = MFMA16(ah1, wl, c, 0, 0, 0);
            c = MFMA16(al1, wh, c, 0, 0, 0);
            acc[1][j] = c;
        }
    }
    __syncthreads();
    epiW<5>(acc, bfp + 0 * 160, act, m0, cl, rg0, wn * 5);
    __syncthreads();

    // ---- layers 2, 3 (N=150 -> 10 tiles, 5 per wn)
    layer_mmW<5>(act, Wt + 1 * 51200, Wt + 1 * 51200 + 25600, arow0, koff, cl, wn * 5, acc);
    __syncthreads();
    epiW<5>(acc, bfp + 1 * 160, act, m0, cl, rg0, wn * 5);
    __syncthreads();

    layer_mmW<5>(act, Wt + 2 * 51200, Wt + 2 * 51200 + 25600, arow0, koff, cl, wn * 5, acc);
    __syncthreads();
    epiW<5>(acc, bfp + 2 * 160, act, m0, cl, rg0, wn * 5);
    __syncthreads();

    // ---- layer 4 (N=100 -> 7 tiles: wn=0 takes 4, wn=1 takes 3)
    if (wn == 0)
        layer_mmW<4>(act, Wt + 3 * 51200, Wt + 3 * 51200 + 25600, arow0, koff, cl, 0, acc);
    else
        layer_mmW<3>(act, Wt + 3 * 51200, Wt + 3 * 51200 + 25600, arow0, koff, cl, 4, acc);
    __syncthreads();
    if (wn == 0)
        epiW<4>(acc, bfp + 3 * 160, act, m0, cl, rg0, 0);
    else
        epiW<3>(acc, bfp + 3 * 160, act, m0, cl, rg0, 4);
    __syncthreads();

    // write E transposed bf16: Et[b][j][r], rows j=100..127 zeroed
    for (int idx = t; idx < 64 * 128; idx += 256) {
        int rr = idx & 63, j = idx >> 6;
        size_t gr = row0 + rr;
        int b = (int)(gr / R_);
        int r = (int)(gr - (size_t)b * R_);
        Et[((size_t)(b * EDP_ + j)) * R_ + r] = (j < 100) ? act[rr][j] : (unsigned short)0;
    }
}

// ---------------- Kernel 3: aggregation, M=128 per block --------------------
// per (mt, b, kz): C[128x128] += RR[128 x 800] @ E[800 x 128]
// grid (8, 4, 25), 256 threads = 4 waves; wave w owns rows w*32..w*32+31
// (two 16-row m-groups), all 128 cols (8 n-tiles).
// A: direct per-lane global loads (+f2bf). B: double-buffered LDS
// [2][128][36] (18.4 KB), one barrier per k-step of 32, loads issued early.
__global__ __launch_bounds__(256) void k_agg(
    const float* __restrict__ RRm, const unsigned short* __restrict__ Et,
    float* __restrict__ part)
{
    __shared__ unsigned short sB[2][128][36];   // pad 36: 18-dword row stride
    const int t = threadIdx.x;
    const int mt = blockIdx.x, b = blockIdx.y, kz = blockIdx.z;
    const int lane = t & 63, wave = t >> 6;
    const int k0 = kz * CHUNK_;

    // B-stage: 128 rows x 32 bf16 per k-step = 512 x 16B chunks; 2 per thread
    const int br0 = t >> 2, bc0 = (t & 3) * 8;       // rows 0..63
    const int br1 = br0 + 64;                        // rows 64..127
    const unsigned short* EtB = Et + (size_t)b * EDP_ * R_;

    // A: two per-lane rows (m-groups), clamped (rows >=1000 dup 999; their
    // part rows are padding, never read by k_obj)
    const int cl = lane & 15, koff = (lane >> 4) * 8;
    int n0 = mt * 128 + wave * 32 + cl;
    int n1 = n0 + 16;
    if (n0 > 999) n0 = 999;
    if (n1 > 999) n1 = 999;
    const float* Ap0 = RRm + ((size_t)(b * O_) + n0) * R_ + k0 + koff;
    const float* Ap1 = RRm + ((size_t)(b * O_) + n1) * R_ + k0 + koff;

    f32x4 acc[2][8] = {};
    float4 a0c, a1c, a2c, a3c;
    float4 a0n = {0,0,0,0}, a1n = {0,0,0,0}, a2n = {0,0,0,0}, a3n = {0,0,0,0};

    // prologue: stage B + load A for iter 0
    {
        ushort8v v0 = *(const ushort8v*)(EtB + (size_t)br0 * R_ + k0 + bc0);
        ushort8v v1 = *(const ushort8v*)(EtB + (size_t)br1 * R_ + k0 + bc0);
        *(ushort8v*)&sB[0][br0][bc0] = v0;
        *(ushort8v*)&sB[0][br1][bc0] = v1;
        a0c = *(const float4*)(Ap0 + 0);
        a1c = *(const float4*)(Ap0 + 4);
        a2c = *(const float4*)(Ap1 + 0);
        a3c = *(const float4*)(Ap1 + 4);
    }
    __syncthreads();

    for (int it = 0; it < CHUNK_ / 32; ++it) {
        const int cur = it & 1, nxt = cur ^ 1;
        const bool more = (it + 1 < CHUNK_ / 32);
        ushort8v v0, v1;
        if (more) {
            // issue next-iter loads EARLY (hide HBM latency under MFMA phase)
            const int kb = k0 + (it + 1) * 32;
            v0 = *(const ushort8v*)(EtB + (size_t)br0 * R_ + kb + bc0);
            v1 = *(const ushort8v*)(EtB + (size_t)br1 * R_ + kb + bc0);
            a0n = *(const float4*)(Ap0 + (it + 1) * 32);
            a1n = *(const float4*)(Ap0 + (it + 1) * 32 + 4);
            a2n = *(const float4*)(Ap1 + (it + 1) * 32);
            a3n = *(const float4*)(Ap1 + (it + 1) * 32 + 4);
        }
        // convert A (cur) to bf16 fragments
        bf16x8 af0, af1;
        af0[0] = (short)f2bf(a0c.x); af0[1] = (short)f2bf(a0c.y);
        af0[2] = (short)f2bf(a0c.z); af0[3] = (short)f2bf(a0c.w);
        af0[4] = (short)f2bf(a1c.x); af0[5] = (short)f2bf(a1c.y);
        af0[6] = (short)f2bf(a1c.z); af0[7] = (short)f2bf(a1c.w);
        af1[0] = (short)f2bf(a2c.x); af1[1] = (short)f2bf(a2c.y);
        af1[2] = (short)f2bf(a2c.z); af1[3] = (short)f2bf(a2c.w);
        af1[4] = (short)f2bf(a3c.x); af1[5] = (short)f2bf(a3c.y);
        af1[6] = (short)f2bf(a3c.z); af1[7] = (short)f2bf(a3c.w);
        #pragma unroll
        for (int ni = 0; ni < 8; ++ni) {
            bf16x8 bf = *(const bf16x8*)&sB[cur][ni * 16 + cl][koff];
            acc[0][ni] = MFMA16(af0, bf, acc[0][ni], 0, 0, 0);
            acc[1][ni] = MFMA16(af1, bf, acc[1][ni], 0, 0, 0);
        }
        if (more) {
            *(ushort8v*)&sB[nxt][br0][bc0] = v0;
            *(ushort8v*)&sB[nxt][br1][bc0] = v1;
        }
        __syncthreads();
        a0c = a0n; a1c = a1n; a2c = a2n; a3c = a3n;
    }

    // store partials: C/D layout col=lane&15, row=(lane>>4)*4+rg
    float* pp = part + ((size_t)(kz * 4 + b) * MPAD_) * 128;
    #pragma unroll
    for (int mg = 0; mg < 2; ++mg) {
        const int rowb = mt * 128 + wave * 32 + mg * 16 + (lane >> 4) * 4;
        #pragma unroll
        for (int ni = 0; ni < 8; ++ni)
            #pragma unroll
            for (int rg = 0; rg < 4; ++rg)
                pp[(size_t)(rowb + rg) * 128 + ni * 16 + cl] = acc[mg][ni][rg];
    }
}

// ---------------- Kernel 4: object MLP (sums agg partials) ------------------
__global__ __launch_bounds__(256) void k_obj(
    const float* __restrict__ obj, const float* __restrict__ part,
    const float* __restrict__ ow1, const float* __restrict__ ob1,
    const float* __restrict__ ow2, const float* __restrict__ ob2,
    float* __restrict__ out)
{
    __shared__ float C[8][112];
    __shared__ float h[8][104];
    const int t = threadIdx.x;
    const int g0 = blockIdx.x * 8;

    for (int idx = t; idx < 8 * NF_; idx += 256) {
        int rr = idx / NF_, f = idx % NF_;
        C[rr][f] = obj[(size_t)(g0 + rr) * NF_ + f];
    }
    for (int idx = t; idx < 8 * 100; idx += 256) {
        int rr = idx / 100, f = idx % 100;
        int g = g0 + rr, b = g / 1000, n = g % 1000;
        float s = 0.f;
        for (int z = 0; z < KS_; ++z)
            s += part[((size_t)(z * 4 + b) * MPAD_ + n) * 128 + f];
        C[rr][6 + f] = s;
    }
    __syncthreads();

    for (int idx = t; idx < 8 * 100; idx += 256) {
        int rr = idx / 100, j = idx % 100;
        float acc = ob1[j];
        for (int k = 0; k < 106; ++k)
            acc = fmaf(C[rr][k], ow1[k * 100 + j], acc);
        h[rr][j] = fmaxf(acc, 0.f);
    }
    __syncthreads();

    if (t < 16) {
        int rr = t >> 1, j = t & 1;
        float acc = ob2[j];
        for (int k = 0; k < 100; ++k)
            acc = fmaf(h[rr][k], ow2[k * 2 + j], acc);
        out[(size_t)(g0 + rr) * 2 + j] = acc;
    }
}

// ---------------- launch ----------------------------------------------------
extern "C" void kernel_launch(void* const* d_in, const int* in_sizes, int n_in,
                              void* d_out, int out_size, void* d_ws, size_t ws_size,
                              hipStream_t stream)
{
    const float* obj   = (const float*)d_in[0];
    const float* S     = (const float*)d_in[1];
    const float* RRm   = (const float*)d_in[2];
    const float* rinfo = (const float*)d_in[3];
    const float* rw1   = (const float*)d_in[4];
    const float* rb1   = (const float*)d_in[5];
    const float* rw2   = (const float*)d_in[6];
    const float* rb2   = (const float*)d_in[7];
    const float* rw3   = (const float*)d_in[8];
    const float* rb3   = (const float*)d_in[9];
    const float* rw4   = (const float*)d_in[10];
    const float* rb4   = (const float*)d_in[11];
    const float* ow1   = (const float*)d_in[12];
    const float* ob1   = (const float*)d_in[13];
    const float* ow2   = (const float*)d_in[14];
    const float* ob2   = (const float*)d_in[15];

    float* ws            = (float*)d_ws;
    float* bmp           = ws;
    unsigned short* Et   = (unsigned short*)(ws + ET_OFF);
    float* part          = ws + PART_OFF;
    unsigned short* Wt   = (unsigned short*)(ws + PART_OFF);  // aliases part head
    float* bfp           = ws + PART_OFF + (WT_USHORTS / 2);
    float* out           = (float*)d_out;

    k_prep<<<dim3(100, 4), 256, 0, stream>>>(rw1, rb1, rw2, rb2, rw3, rb3, rw4, rb4,
                                             Wt, bfp);
    k_marshal<<<dim3(79, 4, 2), 256, 0, stream>>>(obj, S, RRm, rinfo, bmp);
    k_mlp<<<dim3(1250), 256, 0, stream>>>(bmp, Et, Wt, bfp);
    k_agg<<<dim3(8, 4, KS_), 256, 0, stream>>>(RRm, Et, part);
    k_obj<<<dim3(500), 256, 0, stream>>>(obj, part, ow1, ob1, ow2, ob2, out);
}